// Round 5
// baseline (151.380 us; speedup 1.0000x reference)
//
#include <hip/hip_runtime.h>
#include <hip/hip_bf16.h>
#include <hip/hip_fp16.h>

typedef _Float16 f16;
typedef __attribute__((ext_vector_type(2))) _Float16 h2v;
typedef __attribute__((ext_vector_type(8))) _Float16 f16x8;  // MFMA A/B frag (4 VGPR)
typedef __attribute__((ext_vector_type(4))) float f32x4;     // MFMA C/D frag

#define B_    2
#define C_    256
#define O_    256
#define H_    96
#define W_    96
#define HW_   9216
#define PADP  8
#define XP_   112            // 96 + 2*8 halo
#define XPXP_ 12544          // 112*112
#define NS_   36             // K-slices: 2304/64
#define NBLK  576            // 288 m-tiles (64 rows of b*H*W) * 2 o-halves
#define XT_ELEMS   (B_*XPXP_*C_)   // 6,422,528 f16
#define BMAT_ELEMS (NS_*16384)     // 589,824 f16

#define GLOAD_LDS16(g, l) \
  __builtin_amdgcn_global_load_lds((const __attribute__((address_space(1))) void*)(g), \
                                   (__attribute__((address_space(3))) void*)(l), 16, 0, 0)

union U4 { uint4 u; h2v h[4]; f16x8 v; };
union U1 { unsigned u; h2v h; };

// ---------- prep 1: x (B,C,H,W) f32 -> xT[b][y+8][x+8][c] f16, halo pre-zeroed ----------
__global__ __launch_bounds__(256) void k_prep_x(const float* __restrict__ x, f16* __restrict__ xT) {
    __shared__ float tile[64 * 97];
    int blk = blockIdx.x;                      // ((b*96)+y)*4 + cg
    int cg  = blk & 3;
    int y   = (blk >> 2) % 96;
    int b   = blk / 384;
    int t   = threadIdx.x;
    const float* src = x + (((size_t)(b*256 + cg*64))*96 + y)*96;
    for (int e = t; e < 6144; e += 256) {
        int c = e / 96, wcol = e - c*96;
        tile[c*97 + wcol] = src[(size_t)c*HW_ + wcol];
    }
    __syncthreads();
    f16* dst = xT + ((size_t)b*XPXP_ + (size_t)(y+PADP)*XP_ + PADP)*256 + cg*64;
    for (int e = t; e < 6144; e += 256) {
        int wcol = e >> 6, c = e & 63;
        dst[(size_t)wcol*256 + c] = (f16)tile[c*97 + wcol];
    }
}

// ---------- prep 2: weight (O,C,3,3) f32 -> f16 [slice][ohalf][op(128)][j(64)], pre-swizzled ----------
__global__ __launch_bounds__(256) void k_prep_w(const float* __restrict__ wgt, f16* __restrict__ bmat) {
    int id = blockIdx.x*256 + threadIdx.x;     // < 589824
    int s = id >> 14, r = id & 16383;
    int o = r >> 6,  j = r & 63;
    int c = ((s & 3) << 6) + j;
    int k = s >> 2;
    float v = wgt[((size_t)o*256 + c)*9 + k];
    int oh = o >> 7, op = o & 127;
    int swz = ((op << 6) + j) ^ ((op & 7) << 3);
    bmat[(s << 14) + (oh << 13) + swz] = (f16)v;
}

// ---------- main: fused deformable-sample + implicit GEMM, wave-private A ----------
// BM=64 flattened (b,hw) rows x BN=128 o. 4 waves, wave tile 16x128; A frags computed
// directly in registers (packed f16 bilinear), B double-buffered in LDS, ONE barrier/slice.

#define TAPS(t_, tap) do { \
    int kn_ = (t_) >> 2; \
    int i00_ = geo_i[kn_*64 + wrow]; \
    const char* pb_ = xbC + i00_ + ((((t_)&3) << 7) + ((lane >> 4) << 4)); \
    _Pragma("unroll") \
    for (int kh_ = 0; kh_ < 2; ++kh_) { \
      const char* p_ = pb_ + (kh_ << 6); \
      tap[kh_*4+0] = *(const uint4*)(p_); \
      tap[kh_*4+1] = *(const uint4*)(p_ + 512); \
      tap[kh_*4+2] = *(const uint4*)(p_ + 57344); \
      tap[kh_*4+3] = *(const uint4*)(p_ + 57856); \
    } } while (0)

#define BIL(kh_, tapC, afout) do { \
    U4 t0_, t1_, t2_, t3_, oo_; \
    t0_.u = tapC[(kh_)*4+0]; t1_.u = tapC[(kh_)*4+1]; \
    t2_.u = tapC[(kh_)*4+2]; t3_.u = tapC[(kh_)*4+3]; \
    _Pragma("unroll") \
    for (int j_ = 0; j_ < 4; ++j_) \
      oo_.h[j_] = w00*t0_.h[j_] + w01*t1_.h[j_] + w10*t2_.h[j_] + w11*t3_.h[j_]; \
    afout = oo_.v; } while (0)

#define STEP(s_, CUR, NXT, tapC, tapN, PF) do { \
    U4 WQ; WQ.u = geo_w[((s_) >> 2)*64 + wrow]; \
    h2v w00 = WQ.h[0], w01 = WQ.h[1], w10 = WQ.h[2], w11 = WQ.h[3]; \
    f16x8 af0, af1; \
    BIL(0, tapC, af0); \
    BIL(1, tapC, af1); \
    asm volatile("s_waitcnt vmcnt(0)" ::: "memory"); \
    __builtin_amdgcn_sched_barrier(0); \
    __builtin_amdgcn_s_barrier(); \
    __builtin_amdgcn_sched_barrier(0); \
    if (PF) { \
      const char* gb = bmatC + ((size_t)((s_)+1) << 15) + (oh << 14); \
      _Pragma("unroll") \
      for (int i_ = 0; i_ < 4; ++i_) \
        GLOAD_LDS16(gb + (i_<<12) + (tid<<4), bsC + (NXT)*16384 + (i_<<12) + (tid<<4)); \
      TAPS((s_)+1, tapN); \
    } \
    __builtin_amdgcn_sched_barrier(0); \
    __builtin_amdgcn_s_setprio(1); \
    _Pragma("unroll") \
    for (int kh_ = 0; kh_ < 2; ++kh_) { \
      int kb_ = (kh_ << 6) + ((lane >> 4) << 4); \
      f16x8 afk = kh_ ? af1 : af0; \
      _Pragma("unroll") \
      for (int fn_ = 0; fn_ < 8; ++fn_) { \
        int op_ = fn_*16 + (lane & 15); \
        f16x8 bfr = *(const f16x8*)(bsC + ((((op_ << 7) + kb_) ^ ((op_ & 7) << 4)) + (CUR)*16384)); \
        acc[fn_] = __builtin_amdgcn_mfma_f32_16x16x32_f16(afk, bfr, acc[fn_], 0, 0, 0); \
      } \
    } \
    __builtin_amdgcn_s_setprio(0); \
    __builtin_amdgcn_sched_barrier(0); \
  } while (0)

__global__ __launch_bounds__(256, 3) void k_main(
        const f16* __restrict__ xT, const f16* __restrict__ bmat,
        const float* __restrict__ offs, const float* __restrict__ maskp,
        const float* __restrict__ bias, float* __restrict__ out,
        float* __restrict__ part)
{
    __shared__ __align__(16) char BsLDS[2*16384];   // 32 KB, double-buffered B (pre-swz global, linear dest)
    __shared__ int   geo_i[576];                    // 9 k * 64 rows, byte offsets
    __shared__ uint4 geo_w[576];                    // 4 replicated-f16-pair bilinear weights (mask folded)
    __shared__ float psum[4][8][2];

    char* bsC = BsLDS;

    int blk0 = blockIdx.x;                      // 0..575
    int blk  = (blk0 & 7)*72 + (blk0 >> 3);     // bijective XCD-chunked swizzle (576%8==0)
    int oh   = blk & 1;
    int mblk = blk >> 1;                        // 0..287
    int b    = mblk / 144;
    int hw0  = (mblk - b*144) * 64;

    int tid  = threadIdx.x;
    int lane = tid & 63;
    int wid  = tid >> 6;
    int wrow = wid*16 + (lane & 15);

    // ---- geometry for all 9 kernel positions x 64 rows, once ----
    for (int e = tid; e < 576; e += 256) {
        int k = e >> 6, r = e & 63;
        int hw = hw0 + r;
        int h = hw / 96, w = hw - h*96;
        float offy = offs[((size_t)b*18 + 2*k)*HW_ + hw];
        float offx = offs[((size_t)b*18 + 2*k + 1)*HW_ + hw];
        float mv   = maskp[((size_t)b*9 + k)*HW_ + hw];
        int ky = k/3 - 1, kx = k - (k/3)*3 - 1;
        float py = (float)(h + ky) + offy;
        float px = (float)(w + kx) + offx;
        py = fminf(fmaxf(py, -7.5f), 102.4f);   // keep taps inside zero halo
        px = fminf(fmaxf(px, -7.5f), 102.4f);
        float y0 = floorf(py), x0 = floorf(px);
        float dy = py - y0,   dx = px - x0;
        geo_i[e] = (((int)y0 + PADP)*XP_ + ((int)x0 + PADP)) << 9;  // byte offset
        float w00v = (1.f-dy)*(1.f-dx)*mv, w01v = (1.f-dy)*dx*mv;
        float w10v = dy*(1.f-dx)*mv,       w11v = dy*dx*mv;
        U1 p0, p1, p2, p3;
        p0.h = h2v{(f16)w00v, (f16)w00v};
        p1.h = h2v{(f16)w01v, (f16)w01v};
        p2.h = h2v{(f16)w10v, (f16)w10v};
        p3.h = h2v{(f16)w11v, (f16)w11v};
        geo_w[e] = uint4{p0.u, p1.u, p2.u, p3.u};
    }
    __syncthreads();

    f32x4 acc[8];
    #pragma unroll
    for (int i = 0; i < 8; ++i) acc[i] = (f32x4){0.f,0.f,0.f,0.f};

    const char* xbC   = (const char*)xT + (size_t)b*XPXP_*512;
    const char* bmatC = (const char*)bmat;
    uint4 tapA[8], tapB[8];

    // ---- prologue: B(0) -> buf0, taps(0) -> tapA ----
    {
        const char* gb = bmatC + (oh << 14);
        #pragma unroll
        for (int i = 0; i < 4; ++i)
            GLOAD_LDS16(gb + (i<<12) + (tid<<4), bsC + (i<<12) + (tid<<4));
    }
    TAPS(0, tapA);

    for (int sp = 0; sp < 34; sp += 2) {
        STEP(sp,   0, 1, tapA, tapB, 1);
        STEP(sp+1, 1, 0, tapB, tapA, 1);
    }
    STEP(34, 0, 1, tapA, tapB, 1);
    STEP(35, 1, 0, tapB, tapA, 0);

    // ---- epilogue: bias + store + per-group partial stats ----
    int ol = lane & 15;
    #pragma unroll
    for (int fn = 0; fn < 8; ++fn) {
        int o = oh*128 + fn*16 + ol;
        float bv = bias[o];
        f32x4 a = acc[fn];
        a[0] += bv; a[1] += bv; a[2] += bv; a[3] += bv;
        acc[fn] = a;
        int ml = wid*16 + ((lane >> 4) << 2);
        *(float4*)(out + ((size_t)(b*256 + o))*HW_ + hw0 + ml) = make_float4(a[0], a[1], a[2], a[3]);
    }
    #pragma unroll
    for (int fn = 0; fn < 8; ++fn) {            // group = 16 consecutive o = one fn frag
        f32x4 a = acc[fn];
        float s1 = a[0]+a[1]+a[2]+a[3];
        float s2 = a[0]*a[0]+a[1]*a[1]+a[2]*a[2]+a[3]*a[3];
        #pragma unroll
        for (int m = 32; m > 0; m >>= 1) {
            s1 += __shfl_xor(s1, m);
            s2 += __shfl_xor(s2, m);
        }
        if (lane == 0) { psum[wid][fn][0] = s1; psum[wid][fn][1] = s2; }
    }
    __syncthreads();
    if (tid < 8) {
        float s1 = psum[0][tid][0] + psum[1][tid][0] + psum[2][tid][0] + psum[3][tid][0];
        float s2 = psum[0][tid][1] + psum[1][tid][1] + psum[2][tid][1] + psum[3][tid][1];
        part[(size_t)blk*16 + tid*2]     = s1;
        part[(size_t)blk*16 + tid*2 + 1] = s2;
    }
}

// ---------- finalize GN stats: 32 blocks, one per (b,g) ----------
__global__ __launch_bounds__(256) void k_finalize(const float* __restrict__ part, float* __restrict__ stats) {
    int bg = blockIdx.x, b = bg >> 4, g = bg & 15;
    int ohh = g >> 3, gl = g & 7;
    float s1 = 0.f, s2 = 0.f;
    for (int j = threadIdx.x; j < 144; j += 256) {
        int mblk = b*144 + j;
        const float* p = part + ((size_t)(mblk*2 + ohh)*16 + gl*2);
        s1 += p[0]; s2 += p[1];
    }
    __shared__ float a1[256], a2[256];
    a1[threadIdx.x] = s1; a2[threadIdx.x] = s2;
    __syncthreads();
    for (int off = 128; off > 0; off >>= 1) {
        if (threadIdx.x < off) { a1[threadIdx.x] += a1[threadIdx.x+off]; a2[threadIdx.x] += a2[threadIdx.x+off]; }
        __syncthreads();
    }
    if (threadIdx.x == 0) {
        float inv_n = 1.f/147456.f;
        float mean = a1[0]*inv_n;
        float var  = fmaxf(a2[0]*inv_n - mean*mean, 0.f);
        stats[bg*2]   = mean;
        stats[bg*2+1] = rsqrtf(var + 1e-5f);
    }
}

// ---------- normalize in place ----------
__global__ __launch_bounds__(256) void k_norm(float* __restrict__ out, const float* __restrict__ stats,
                                              const float* __restrict__ gamma, const float* __restrict__ beta) {
    int i4 = blockIdx.x*256 + threadIdx.x;             // < 1179648 float4s
    int p  = i4 / 2304;                                // = b*256+o
    int o  = p & 255;
    float mean = stats[(p>>4)*2], rstd = stats[(p>>4)*2 + 1];
    float ga = gamma[o], be = beta[o];
    float4 v = ((const float4*)out)[i4];
    v.x = (v.x-mean)*rstd*ga + be;
    v.y = (v.y-mean)*rstd*ga + be;
    v.z = (v.z-mean)*rstd*ga + be;
    v.w = (v.w-mean)*rstd*ga + be;
    ((float4*)out)[i4] = v;
}

extern "C" void kernel_launch(void* const* d_in, const int* in_sizes, int n_in,
                              void* d_out, int out_size, void* d_ws, size_t ws_size,
                              hipStream_t stream) {
    const float* x      = (const float*)d_in[0];
    const float* offset = (const float*)d_in[1];
    const float* mask   = (const float*)d_in[2];
    const float* weight = (const float*)d_in[3];
    const float* bias   = (const float*)d_in[4];
    const float* gamma  = (const float*)d_in[5];
    const float* beta   = (const float*)d_in[6];
    float* out = (float*)d_out;

    f16* xT    = (f16*)d_ws;
    f16* bmat  = xT + XT_ELEMS;
    float* part  = (float*)(bmat + BMAT_ELEMS);        // NBLK*16 floats
    float* stats = part + NBLK*16;                     // 64 floats

    (void)hipMemsetAsync(xT, 0, (size_t)XT_ELEMS*sizeof(f16), stream);  // zero halo
    k_prep_x<<<768, 256, 0, stream>>>(x, xT);
    k_prep_w<<<2304, 256, 0, stream>>>(weight, bmat);
    k_main<<<NBLK, 256, 0, stream>>>(xT, bmat, offset, mask, bias, out, part);
    k_finalize<<<32, 256, 0, stream>>>(part, stats);
    k_norm<<<4608, 256, 0, stream>>>(out, stats, gamma, beta);
}

// Round 6
// 144.386 us; speedup vs baseline: 1.0484x; 1.0484x over previous
//
#include <hip/hip_runtime.h>
#include <hip/hip_bf16.h>
#include <hip/hip_fp16.h>

typedef _Float16 f16;
typedef __attribute__((ext_vector_type(2))) _Float16 h2v;
typedef __attribute__((ext_vector_type(8))) _Float16 f16x8;  // MFMA A/B frag (4 VGPR)
typedef __attribute__((ext_vector_type(4))) float f32x4;     // MFMA C/D frag

#define B_    2
#define C_    256
#define O_    256
#define H_    96
#define W_    96
#define HW_   9216
#define PADP  8
#define XP_   112            // 96 + 2*8 halo
#define XPXP_ 12544          // 112*112
#define NSTEP 36             // K-steps: 2304/64
#define NBLK  768            // 384 m-tiles (48 rows) * 2 o-halves -> exactly 3 blocks/CU
#define XT_ELEMS   (B_*XPXP_*C_)   // 6,422,528 f16
#define BMAT_ELEMS (NSTEP*16384)   // 589,824 f16

#define GLOAD_LDS16(g, l) \
  __builtin_amdgcn_global_load_lds((const __attribute__((address_space(1))) void*)(g), \
                                   (__attribute__((address_space(3))) void*)(l), 16, 0, 0)

union U4 { uint4 u; h2v h[4]; f16x8 v; };
union U1 { unsigned u; h2v h; };

// ---------- prep 1: x (B,C,H,W) f32 -> xT[b][y+8][x+8][c] f16, halo pre-zeroed ----------
__global__ __launch_bounds__(256) void k_prep_x(const float* __restrict__ x, f16* __restrict__ xT) {
    __shared__ float tile[64 * 97];
    int blk = blockIdx.x;                      // ((b*96)+y)*4 + cg
    int cg  = blk & 3;
    int y   = (blk >> 2) % 96;
    int b   = blk / 384;
    int t   = threadIdx.x;
    const float* src = x + (((size_t)(b*256 + cg*64))*96 + y)*96;
    for (int e = t; e < 6144; e += 256) {
        int c = e / 96, wcol = e - c*96;
        tile[c*97 + wcol] = src[(size_t)c*HW_ + wcol];
    }
    __syncthreads();
    f16* dst = xT + ((size_t)b*XPXP_ + (size_t)(y+PADP)*XP_ + PADP)*256 + cg*64;
    for (int e = t; e < 6144; e += 256) {
        int wcol = e >> 6, c = e & 63;
        dst[(size_t)wcol*256 + c] = (f16)tile[c*97 + wcol];
    }
}

// ---------- prep 2: weight (O,C,3,3) f32 -> f16 fragment-major ----------
// step s = k*4 + (c>>6); dest block per (s, oh=o>>7) of 8192 elems:
//   [fn = (o>>4)&7][kc = (c>>5)&1][lane = ((c>>3)&3)*16 + (o&15)][e = c&7]
__global__ __launch_bounds__(256) void k_prep_w(const float* __restrict__ wgt, f16* __restrict__ bmat) {
    int id = blockIdx.x*256 + threadIdx.x;     // < 589824 = (o*256+c)*9+k
    int o = id / 2304;
    int rem = id - o*2304;
    int c = rem / 9;
    int k = rem - c*9;
    int s  = k*4 + (c >> 6);
    int oh = o >> 7, fn = (o >> 4) & 7, r = o & 15;
    int kc = (c >> 5) & 1, q = (c >> 3) & 3, e = c & 7;
    size_t dest = (size_t)(s*2 + oh)*8192 + fn*1024 + kc*512 + (q*16 + r)*8 + e;
    bmat[dest] = (f16)wgt[id];
}

// ---------- main: fused deformable-sample + implicit GEMM ----------
// BM=48 x BN=128, BK=64/step. 6 waves = 3(m) x 2(kc K-split). A-frags in registers
// (packed-f16 bilinear), B double-buffered LDS (fragment-major), ONE barrier/step,
// counted vmcnt, taps prefetched pre-barrier.

#define TAPS(t_) do { \
    int k_  = (t_) >> 2; \
    int i00_ = geo_i[k_*48 + wrow]; \
    const char* p_ = xbC + i00_ + (((t_) & 3) << 7) + laneCOfs; \
    tap0 = *(const uint4*)(p_); \
    tap1 = *(const uint4*)(p_ + 512); \
    tap2 = *(const uint4*)(p_ + 57344); \
    tap3 = *(const uint4*)(p_ + 57856); \
  } while (0)

#define BIL(t_, afOut) do { \
    U4 WQ; WQ.u = geo_w[((t_) >> 2)*48 + wrow]; \
    h2v w00 = WQ.h[0], w01 = WQ.h[1], w10 = WQ.h[2], w11 = WQ.h[3]; \
    U4 t0_, t1_, t2_, t3_, oo_; \
    t0_.u = tap0; t1_.u = tap1; t2_.u = tap2; t3_.u = tap3; \
    _Pragma("unroll") \
    for (int j_ = 0; j_ < 4; ++j_) \
      oo_.h[j_] = w00*t0_.h[j_] + w01*t1_.h[j_] + w10*t2_.h[j_] + w11*t3_.h[j_]; \
    afOut = oo_.v; \
  } while (0)

#define STAGE(t_, BUF) do { \
    const char* gb_ = bmatC + (size_t)((t_)*2 + oh)*16384; \
    GLOAD_LDS16(gb_ + (tid << 4),         bsC + (BUF)*16384 + (tid << 4)); \
    GLOAD_LDS16(gb_ + ((tid+384) << 4),   bsC + (BUF)*16384 + ((tid+384) << 4)); \
    if (tid < 256) \
      GLOAD_LDS16(gb_ + ((tid+768) << 4), bsC + (BUF)*16384 + ((tid+768) << 4)); \
  } while (0)

#define ITER(s_, CUR, afC, afN, PF) do { \
    if (PF) { TAPS((s_)+1); } \
    __builtin_amdgcn_sched_barrier(0); \
    asm volatile("s_waitcnt vmcnt(%0)" :: "i"((PF) ? 4 : 0) : "memory"); \
    __builtin_amdgcn_sched_barrier(0); \
    __builtin_amdgcn_s_barrier(); \
    __builtin_amdgcn_sched_barrier(0); \
    if (PF) { STAGE((s_)+1, 1-(CUR)); } \
    __builtin_amdgcn_s_setprio(1); \
    _Pragma("unroll") \
    for (int fn_ = 0; fn_ < 8; ++fn_) { \
      f16x8 bf_ = *(const f16x8*)(bsC + (CUR)*16384 + fn_*2048 + kcOff + (lane << 4)); \
      acc[fn_] = __builtin_amdgcn_mfma_f32_16x16x32_f16(afC, bf_, acc[fn_], 0, 0, 0); \
    } \
    __builtin_amdgcn_s_setprio(0); \
    __builtin_amdgcn_sched_barrier(0); \
    if (PF) { BIL((s_)+1, afN); } \
  } while (0)

__global__ __launch_bounds__(384, 5) void k_main(
        const f16* __restrict__ xT, const f16* __restrict__ bmat,
        const float* __restrict__ offs, const float* __restrict__ maskp,
        const float* __restrict__ bias, float* __restrict__ out,
        float* __restrict__ part)
{
    __shared__ __align__(16) char BsLDS[2*16384];   // 32 KB double-buffered B, fragment-major
    __shared__ int   geo_i[432];                    // 9k * 48 rows, byte offsets into xT image
    __shared__ uint4 geo_w[432];                    // replicated-h2 bilinear weights (mask folded)
    __shared__ float psum[3][8][2];

    char* bsC = BsLDS;

    int blk0 = blockIdx.x;                      // 0..767
    int blk  = (blk0 & 7)*96 + (blk0 >> 3);     // bijective XCD-chunked swizzle (768%8==0)
    int oh = blk & 1;
    int mt = blk >> 1;                          // 0..383
    int b  = mt / 192;
    int hw0 = (mt - b*192) * 48;                // within-image row offset
    int h  = hw0 / 96;
    int w0 = hw0 - h*96;                        // 0 or 48

    int tid  = threadIdx.x;
    int lane = tid & 63;
    int wid  = tid >> 6;
    int wm = wid >> 1;                          // 0..2: m-group (16 rows)
    int kc = wid & 1;                           // 0..1: K-half of each 64-ch step
    int wrow = wm*16 + (lane & 15);             // this lane's m-row (0..47)
    int laneCOfs = kc*64 + ((lane >> 4) << 4);  // byte offset within pixel's 512B
    int kcOff = kc * 1024;                      // B-frag byte offset

    // ---- geometry for all 9 kernel positions x 48 rows, once ----
    for (int e = tid; e < 432; e += 384) {
        int k = e / 48, ww = e - k*48;
        int w = w0 + ww;
        float offy = offs[(((size_t)b*18 + 2*k    )*96 + h)*96 + w];
        float offx = offs[(((size_t)b*18 + 2*k + 1)*96 + h)*96 + w];
        float mv   = maskp[(((size_t)b*9 + k)*96 + h)*96 + w];
        int ky = k/3 - 1, kx = k - (k/3)*3 - 1;
        float py = (float)(h + ky) + offy;
        float px = (float)(w + kx) + offx;
        py = fminf(fmaxf(py, -7.5f), 102.4f);   // keep taps inside zero halo
        px = fminf(fmaxf(px, -7.5f), 102.4f);
        float y0 = floorf(py), x0 = floorf(px);
        float dy = py - y0,   dx = px - x0;
        geo_i[e] = (((int)y0 + PADP)*XP_ + ((int)x0 + PADP)) << 9;  // byte offset (512B/pixel)
        float w00v = (1.f-dy)*(1.f-dx)*mv, w01v = (1.f-dy)*dx*mv;
        float w10v = dy*(1.f-dx)*mv,       w11v = dy*dx*mv;
        U1 p0, p1, p2, p3;
        p0.h = h2v{(f16)w00v, (f16)w00v};
        p1.h = h2v{(f16)w01v, (f16)w01v};
        p2.h = h2v{(f16)w10v, (f16)w10v};
        p3.h = h2v{(f16)w11v, (f16)w11v};
        geo_w[e] = uint4{p0.u, p1.u, p2.u, p3.u};
    }
    __syncthreads();

    f32x4 acc[8];
    #pragma unroll
    for (int i = 0; i < 8; ++i) acc[i] = (f32x4){0.f,0.f,0.f,0.f};

    const char* xbC   = (const char*)xT + (size_t)b*XPXP_*512;
    const char* bmatC = (const char*)bmat;
    uint4 tap0, tap1, tap2, tap3;
    f16x8 afA, afB;

    // ---- prologue: B(0) -> buf0 first, then taps(0), BIL(0) ----
    STAGE(0, 0);
    TAPS(0);
    BIL(0, afA);                                // waits taps(0); FIFO => B(0) also retired by then

    for (int sp = 0; sp < 34; sp += 2) {
        ITER(sp,   0, afA, afB, 1);
        ITER(sp+1, 1, afB, afA, 1);
    }
    ITER(34, 0, afA, afB, 1);
    ITER(35, 1, afB, afA, 0);

    // ---- epilogue: merge kc-halves, bias, store, per-group partial stats ----
    __syncthreads();                            // all MFMA done; Bs reusable as scratch
    if (kc == 1) {
        #pragma unroll
        for (int fn = 0; fn < 8; ++fn)
            *(f32x4*)(bsC + (((wm*8 + fn)*64 + lane) << 4)) = acc[fn];
    }
    __syncthreads();
    if (kc == 0) {
        int ol = lane & 15;
        #pragma unroll
        for (int fn = 0; fn < 8; ++fn) {
            f32x4 p = *(const f32x4*)(bsC + (((wm*8 + fn)*64 + lane) << 4));
            f32x4 a = acc[fn];
            a[0] += p[0]; a[1] += p[1]; a[2] += p[2]; a[3] += p[3];
            int o = oh*128 + fn*16 + ol;
            float bv = bias[o];
            a[0] += bv; a[1] += bv; a[2] += bv; a[3] += bv;
            int ml = wm*16 + ((lane >> 4) << 2);
            *(float4*)(out + ((size_t)(b*256 + o))*HW_ + hw0 + ml)
                = make_float4(a[0], a[1], a[2], a[3]);
            float s1 = a[0]+a[1]+a[2]+a[3];
            float s2 = a[0]*a[0]+a[1]*a[1]+a[2]*a[2]+a[3]*a[3];
            #pragma unroll
            for (int m = 32; m > 0; m >>= 1) {
                s1 += __shfl_xor(s1, m);
                s2 += __shfl_xor(s2, m);
            }
            if (lane == 0) { psum[wm][fn][0] = s1; psum[wm][fn][1] = s2; }
        }
    }
    __syncthreads();
    if (tid < 8) {                              // group-local = fn; global g = oh*8 + fn
        float s1 = psum[0][tid][0] + psum[1][tid][0] + psum[2][tid][0];
        float s2 = psum[0][tid][1] + psum[1][tid][1] + psum[2][tid][1];
        part[(size_t)blk*16 + tid*2]     = s1;
        part[(size_t)blk*16 + tid*2 + 1] = s2;
    }
}

// ---------- finalize GN stats: 32 blocks, one per (b,g) ----------
__global__ __launch_bounds__(256) void k_finalize(const float* __restrict__ part, float* __restrict__ stats) {
    int bg = blockIdx.x, b = bg >> 4, g = bg & 15;
    int oh = g >> 3, fn = g & 7;
    float s1 = 0.f, s2 = 0.f;
    if (threadIdx.x < 192) {
        int mt = b*192 + threadIdx.x;
        int blk = mt*2 + oh;
        s1 = part[(size_t)blk*16 + fn*2];
        s2 = part[(size_t)blk*16 + fn*2 + 1];
    }
    __shared__ float a1[256], a2[256];
    a1[threadIdx.x] = s1; a2[threadIdx.x] = s2;
    __syncthreads();
    for (int off = 128; off > 0; off >>= 1) {
        if (threadIdx.x < off) { a1[threadIdx.x] += a1[threadIdx.x+off]; a2[threadIdx.x] += a2[threadIdx.x+off]; }
        __syncthreads();
    }
    if (threadIdx.x == 0) {
        float inv_n = 1.f/147456.f;
        float mean = a1[0]*inv_n;
        float var  = fmaxf(a2[0]*inv_n - mean*mean, 0.f);
        stats[bg*2]   = mean;
        stats[bg*2+1] = rsqrtf(var + 1e-5f);
    }
}

// ---------- normalize in place ----------
__global__ __launch_bounds__(256) void k_norm(float* __restrict__ out, const float* __restrict__ stats,
                                              const float* __restrict__ gamma, const float* __restrict__ beta) {
    int i4 = blockIdx.x*256 + threadIdx.x;             // < 1179648 float4s
    int p  = i4 / 2304;                                // = b*256+o
    int o  = p & 255;
    float mean = stats[(p>>4)*2], rstd = stats[(p>>4)*2 + 1];
    float ga = gamma[o], be = beta[o];
    float4 v = ((const float4*)out)[i4];
    v.x = (v.x-mean)*rstd*ga + be;
    v.y = (v.y-mean)*rstd*ga + be;
    v.z = (v.z-mean)*rstd*ga + be;
    v.w = (v.w-mean)*rstd*ga + be;
    ((float4*)out)[i4] = v;
}

extern "C" void kernel_launch(void* const* d_in, const int* in_sizes, int n_in,
                              void* d_out, int out_size, void* d_ws, size_t ws_size,
                              hipStream_t stream) {
    const float* x      = (const float*)d_in[0];
    const float* offset = (const float*)d_in[1];
    const float* mask   = (const float*)d_in[2];
    const float* weight = (const float*)d_in[3];
    const float* bias   = (const float*)d_in[4];
    const float* gamma  = (const float*)d_in[5];
    const float* beta   = (const float*)d_in[6];
    float* out = (float*)d_out;

    f16* xT    = (f16*)d_ws;
    f16* bmat  = xT + XT_ELEMS;
    float* part  = (float*)(bmat + BMAT_ELEMS);        // NBLK*16 floats
    float* stats = part + NBLK*16;                     // 64 floats

    (void)hipMemsetAsync(xT, 0, (size_t)XT_ELEMS*sizeof(f16), stream);  // zero halo
    k_prep_x<<<768, 256, 0, stream>>>(x, xT);
    k_prep_w<<<2304, 256, 0, stream>>>(weight, bmat);
    k_main<<<NBLK, 384, 0, stream>>>(xT, bmat, offset, mask, bias, out, part);
    k_finalize<<<32, 256, 0, stream>>>(part, stats);
    k_norm<<<4608, 256, 0, stream>>>(out, stats, gamma, beta);
}

// Round 7
// 84.934 us; speedup vs baseline: 1.7823x; 1.7000x over previous
//
#include <hip/hip_runtime.h>
#include <hip/hip_fp16.h>

typedef _Float16 f16;
typedef __attribute__((ext_vector_type(2))) _Float16 h2v;
typedef __attribute__((ext_vector_type(8))) _Float16 f16x8;  // MFMA A/B frag
typedef __attribute__((ext_vector_type(4))) float f32x4;     // MFMA C/D frag

#define HW_    9216
#define PADP   8
#define XP_    112
#define XPXP_  12544
#define NSTEP  36                 // K-steps: 2304/64
#define NMT    288                // 64-row m-tiles
#define XT_BYTES   12845056      // 2*12544*256*2
#define BMAT_BYTES 1179648       // 36*2*128*64*2
#define ATILE_B    294912        // 36 steps * 8192 B per m-tile

#define GLOAD_LDS16(g, l) \
  __builtin_amdgcn_global_load_lds((const __attribute__((address_space(1))) void*)(g), \
                                   (__attribute__((address_space(3))) void*)(l), 16, 0, 0)

union U4 { uint4 u; h2v h[4]; f16x8 v; };
union U1 { unsigned u; h2v h; };

// ---------- prep 1: x (B,C,H,W) f32 -> xT[b][y+8][x+8][c] f16, halo pre-zeroed ----------
__global__ __launch_bounds__(256) void k_prep_x(const float* __restrict__ x, f16* __restrict__ xT) {
    __shared__ float tile[64 * 97];
    int blk = blockIdx.x;                      // ((b*96)+y)*4 + cg
    int cg  = blk & 3;
    int y   = (blk >> 2) % 96;
    int b   = blk / 384;
    int t   = threadIdx.x;
    const float* src = x + (((size_t)(b*256 + cg*64))*96 + y)*96;
    for (int e = t; e < 6144; e += 256) {
        int c = e / 96, wcol = e - c*96;
        tile[c*97 + wcol] = src[(size_t)c*HW_ + wcol];
    }
    __syncthreads();
    f16* dst = xT + ((size_t)b*XPXP_ + (size_t)(y+PADP)*XP_ + PADP)*256 + cg*64;
    for (int e = t; e < 6144; e += 256) {
        int wcol = e >> 6, c = e & 63;
        dst[(size_t)wcol*256 + c] = (f16)tile[c*97 + wcol];
    }
}

// ---------- prep 2: weight (O,C,3,3) f32 -> f16 [s][oh][op(128)][j(64)] XOR-swizzled ----------
__global__ __launch_bounds__(256) void k_prep_w(const float* __restrict__ wgt, f16* __restrict__ bmat) {
    int id = blockIdx.x*256 + threadIdx.x;     // < 589824
    int s = id >> 14, r = id & 16383;
    int o = r >> 6,  j = r & 63;
    int c = ((s & 3) << 6) + j;
    int k = s >> 2;
    float v = wgt[((size_t)o*256 + c)*9 + k];
    int oh = o >> 7, op = o & 127;
    int swz = ((op << 6) + j) ^ ((op & 7) << 3);
    bmat[(s << 14) + (oh << 13) + swz] = (f16)v;
}

// ---------- sampler: deformable bilinear gather -> A matrix, GEMM-tile pre-swizzled ----------
// block = (m-tile of 64 rows, kernel-pos k). 2048 16B-items per block, 8 per thread.
// No barriers in hot loop; TLP hides gather latency.
__global__ __launch_bounds__(256, 6) void k_sample(
        const f16* __restrict__ xT, const float* __restrict__ offs,
        const float* __restrict__ maskp, f16* __restrict__ Ag, int mt0, int nblk)
{
    __shared__ int   geo_i[64];
    __shared__ uint4 geo_w[64];

    int blk0 = blockIdx.x;
    int blk  = (blk0 & 7)*(nblk >> 3) + (blk0 >> 3);  // XCD-chunked, bijective (nblk%8==0)
    int mtl  = blk / 9;
    int k    = blk - mtl*9;
    int mt   = mt0 + mtl;
    int b    = mt / 144;                       // 64-row tiles never cross b (9216=144*64)

    int tid = threadIdx.x;
    if (tid < 64) {
        int hw = mt*64 + tid - b*HW_;
        int h = hw / 96, w = hw - h*96;
        float offy = offs[((size_t)b*18 + 2*k    )*HW_ + hw];
        float offx = offs[((size_t)b*18 + 2*k + 1)*HW_ + hw];
        float mv   = maskp[((size_t)b*9 + k)*HW_ + hw];
        int ky = k/3 - 1, kx = k - (k/3)*3 - 1;
        float py = (float)(h + ky) + offy;
        float px = (float)(w + kx) + offx;
        py = fminf(fmaxf(py, -7.5f), 102.4f);  // keep taps inside zero halo
        px = fminf(fmaxf(px, -7.5f), 102.4f);
        float y0 = floorf(py), x0 = floorf(px);
        float dy = py - y0,   dx = px - x0;
        geo_i[tid] = (((int)y0 + PADP)*XP_ + ((int)x0 + PADP)) << 9;  // 512B/pixel
        float w00v = (1.f-dy)*(1.f-dx)*mv, w01v = (1.f-dy)*dx*mv;
        float w10v = dy*(1.f-dx)*mv,       w11v = dy*dx*mv;
        U1 p0, p1, p2, p3;
        p0.h = h2v{(f16)w00v, (f16)w00v};
        p1.h = h2v{(f16)w01v, (f16)w01v};
        p2.h = h2v{(f16)w10v, (f16)w10v};
        p3.h = h2v{(f16)w11v, (f16)w11v};
        geo_w[tid] = uint4{p0.u, p1.u, p2.u, p3.u};
    }
    __syncthreads();

    const char* xbC = (const char*)xT + (size_t)b*XPXP_*512;
    char* dst = (char*)Ag + (size_t)mtl*ATILE_B;

    #pragma unroll
    for (int j = 0; j < 8; ++j) {
        int item = tid + j*256;                // 0..2047 = 64 rows x 32 chunks(16B)
        int row = item >> 5, chunk = item & 31;
        const char* p = xbC + geo_i[row] + (chunk << 4);
        U4 t0, t1, t2, t3, oo;
        t0.u = *(const uint4*)(p);
        t1.u = *(const uint4*)(p + 512);
        t2.u = *(const uint4*)(p + XP_*512);
        t3.u = *(const uint4*)(p + XP_*512 + 512);
        U4 w4; w4.u = geo_w[row];
        h2v w00 = w4.h[0], w01 = w4.h[1], w10 = w4.h[2], w11 = w4.h[3];
        #pragma unroll
        for (int q = 0; q < 4; ++q)
            oo.h[q] = w00*t0.h[q] + w01*t1.h[q] + w10*t2.h[q] + w11*t3.h[q];
        int s = k*4 + (chunk >> 3);            // K-step
        int byteA = ((row << 7) + ((chunk & 7) << 4)) ^ ((row & 7) << 4);  // GEMM-read swizzle
        *(uint4*)(dst + (size_t)s*8192 + byteA) = oo.u;
    }
}

// ---------- GEMM: A(18432x2304) x B(2304x256) + bias, GN partial stats ----------
// BM=64 BN=128 BK=64, 4 waves (2m x 2n, wave 32x64). Double-buffered LDS via
// global_load_lds, ONE __syncthreads per step (compiler-scheduled, no asm).
__global__ __launch_bounds__(256, 3) void k_gemm(
        const f16* __restrict__ Ag, const f16* __restrict__ bmat,
        const float* __restrict__ bias, float* __restrict__ out,
        float* __restrict__ part, int mt0, int nblk)
{
    __shared__ __align__(16) char LDS[2][24576];    // [buf][A 8KB | B 16KB]
    __shared__ float psum[2][8][2];

    int blk0 = blockIdx.x;
    int blk  = (blk0 & 7)*(nblk >> 3) + (blk0 >> 3);
    int mtl  = blk >> 1;
    int oh   = blk & 1;
    int mt   = mt0 + mtl;

    int tid = threadIdx.x, lane = tid & 63, wid = tid >> 6;
    int wm = wid >> 1, wn = wid & 1;

    const char* aG = (const char*)Ag + (size_t)mtl*ATILE_B;
    const char* bG = (const char*)bmat + (oh << 14);
    char* ldsB = &LDS[0][0];

    f32x4 acc[2][4];
    #pragma unroll
    for (int i = 0; i < 2; ++i)
        #pragma unroll
        for (int j = 0; j < 4; ++j) acc[i][j] = (f32x4){0.f,0.f,0.f,0.f};

#define GSTAGE(s_, buf_) do { \
    const char* ga_ = aG + (size_t)(s_)*8192; \
    GLOAD_LDS16(ga_ + (tid << 4),           ldsB + (buf_)*24576 + (tid << 4)); \
    GLOAD_LDS16(ga_ + ((tid + 256) << 4),   ldsB + (buf_)*24576 + ((tid + 256) << 4)); \
    const char* gb_ = bG + (size_t)(s_)*32768; \
    _Pragma("unroll") \
    for (int i_ = 0; i_ < 4; ++i_) \
      GLOAD_LDS16(gb_ + ((tid + i_*256) << 4), ldsB + (buf_)*24576 + 8192 + ((tid + i_*256) << 4)); \
  } while (0)

    GSTAGE(0, 0);
    for (int s = 0; s < NSTEP; ++s) {
        int cur = s & 1;
        __syncthreads();                        // drains vmcnt: LDS[cur] ready; LDS[cur^1] free
        if (s + 1 < NSTEP) GSTAGE(s + 1, cur ^ 1);
        const char* Lc = ldsB + cur*24576;
        #pragma unroll
        for (int kh = 0; kh < 2; ++kh) {
            int kb = (kh << 6) + ((lane >> 4) << 4);
            int r0 = wm*32 + (lane & 15);
            int r1 = r0 + 16;
            f16x8 a0 = *(const f16x8*)(Lc + (((r0 << 7) + kb) ^ ((r0 & 7) << 4)));
            f16x8 a1 = *(const f16x8*)(Lc + (((r1 << 7) + kb) ^ ((r1 & 7) << 4)));
            #pragma unroll
            for (int fn = 0; fn < 4; ++fn) {
                int op = wn*64 + fn*16 + (lane & 15);
                f16x8 bf = *(const f16x8*)(Lc + 8192 + (((op << 7) + kb) ^ ((op & 7) << 4)));
                acc[0][fn] = __builtin_amdgcn_mfma_f32_16x16x32_f16(a0, bf, acc[0][fn], 0, 0, 0);
                acc[1][fn] = __builtin_amdgcn_mfma_f32_16x16x32_f16(a1, bf, acc[1][fn], 0, 0, 0);
            }
        }
    }

    // ---- epilogue: bias + store + per-group partial stats ----
    int ol = lane & 15;
    int qr = (lane >> 4) << 2;
    int b  = mt / 144;
    int hwb = mt*64 - b*HW_;
    #pragma unroll
    for (int fm = 0; fm < 2; ++fm) {
        int mrow = wm*32 + fm*16 + qr;
        #pragma unroll
        for (int fn = 0; fn < 4; ++fn) {
            int o = oh*128 + wn*64 + fn*16 + ol;
            float bv = bias[o];
            f32x4 a = acc[fm][fn];
            a[0] += bv; a[1] += bv; a[2] += bv; a[3] += bv;
            acc[fm][fn] = a;
            *(float4*)(out + ((size_t)(b*256 + o))*HW_ + hwb + mrow)
                = make_float4(a[0], a[1], a[2], a[3]);
        }
    }
    #pragma unroll
    for (int fn = 0; fn < 4; ++fn) {            // group gl = wn*4+fn (16 consecutive o)
        float s1 = 0.f, s2 = 0.f;
        #pragma unroll
        for (int fm = 0; fm < 2; ++fm) {
            f32x4 a = acc[fm][fn];
            s1 += a[0]+a[1]+a[2]+a[3];
            s2 += a[0]*a[0]+a[1]*a[1]+a[2]*a[2]+a[3]*a[3];
        }
        #pragma unroll
        for (int m = 32; m > 0; m >>= 1) {
            s1 += __shfl_xor(s1, m);
            s2 += __shfl_xor(s2, m);
        }
        if (lane == 0) { psum[wm][wn*4+fn][0] = s1; psum[wm][wn*4+fn][1] = s2; }
    }
    __syncthreads();
    if (tid < 8) {
        float s1 = psum[0][tid][0] + psum[1][tid][0];
        float s2 = psum[0][tid][1] + psum[1][tid][1];
        part[(size_t)(mt*2 + oh)*16 + tid*2]     = s1;
        part[(size_t)(mt*2 + oh)*16 + tid*2 + 1] = s2;
    }
#undef GSTAGE
}

// ---------- finalize GN stats: 32 blocks, one per (b,g) ----------
__global__ __launch_bounds__(256) void k_finalize(const float* __restrict__ part, float* __restrict__ stats) {
    int bg = blockIdx.x, b = bg >> 4, g = bg & 15;
    int oh = g >> 3, gl = g & 7;
    float s1 = 0.f, s2 = 0.f;
    if (threadIdx.x < 144) {
        int mt = b*144 + threadIdx.x;
        const float* p = part + (size_t)(mt*2 + oh)*16 + gl*2;
        s1 = p[0]; s2 = p[1];
    }
    __shared__ float a1[256], a2[256];
    a1[threadIdx.x] = s1; a2[threadIdx.x] = s2;
    __syncthreads();
    for (int off = 128; off > 0; off >>= 1) {
        if (threadIdx.x < off) { a1[threadIdx.x] += a1[threadIdx.x+off]; a2[threadIdx.x] += a2[threadIdx.x+off]; }
        __syncthreads();
    }
    if (threadIdx.x == 0) {
        float inv_n = 1.f/147456.f;
        float mean = a1[0]*inv_n;
        float var  = fmaxf(a2[0]*inv_n - mean*mean, 0.f);
        stats[bg*2]   = mean;
        stats[bg*2+1] = rsqrtf(var + 1e-5f);
    }
}

// ---------- normalize in place ----------
__global__ __launch_bounds__(256) void k_norm(float* __restrict__ out, const float* __restrict__ stats,
                                              const float* __restrict__ gamma, const float* __restrict__ beta) {
    int i4 = blockIdx.x*256 + threadIdx.x;             // < 1179648 float4s
    int p  = i4 / 2304;                                // = b*256+o
    int o  = p & 255;
    float mean = stats[(p>>4)*2], rstd = stats[(p>>4)*2 + 1];
    float ga = gamma[o], be = beta[o];
    float4 v = ((const float4*)out)[i4];
    v.x = (v.x-mean)*rstd*ga + be;
    v.y = (v.y-mean)*rstd*ga + be;
    v.z = (v.z-mean)*rstd*ga + be;
    v.w = (v.w-mean)*rstd*ga + be;
    ((float4*)out)[i4] = v;
}

extern "C" void kernel_launch(void* const* d_in, const int* in_sizes, int n_in,
                              void* d_out, int out_size, void* d_ws, size_t ws_size,
                              hipStream_t stream) {
    const float* x      = (const float*)d_in[0];
    const float* offset = (const float*)d_in[1];
    const float* mask   = (const float*)d_in[2];
    const float* weight = (const float*)d_in[3];
    const float* bias   = (const float*)d_in[4];
    const float* gamma  = (const float*)d_in[5];
    const float* beta   = (const float*)d_in[6];
    float* out = (float*)d_out;

    char* ws = (char*)d_ws;
    f16*   xT    = (f16*)ws;                               // 12,845,056 B
    f16*   bmat  = (f16*)(ws + XT_BYTES);                  //  1,179,648 B
    float* part  = (float*)(ws + XT_BYTES + BMAT_BYTES);   //     36,864 B
    float* stats = (float*)(ws + XT_BYTES + BMAT_BYTES + 36864);  // 256 B
    char*  Ag    = ws + 14061824;                          // A matrix tiles

    size_t needA = (size_t)NMT * ATILE_B;                  // ~85 MB
    size_t avail = ws_size > 14061824 ? ws_size - 14061824 : 0;
    int P = (avail >= needA) ? 1 : ((avail >= needA/2) ? 2 : 4);

    (void)hipMemsetAsync(xT, 0, XT_BYTES, stream);         // zero halo
    k_prep_x<<<768, 256, 0, stream>>>(x, xT);
    k_prep_w<<<2304, 256, 0, stream>>>(weight, bmat);
    int mtn = NMT / P;
    for (int p = 0; p < P; ++p) {
        k_sample<<<mtn*9, 256, 0, stream>>>(xT, offset, mask, (f16*)Ag, p*mtn, mtn*9);
        k_gemm<<<mtn*2, 256, 0, stream>>>((f16*)Ag, bmat, bias, out, part, p*mtn, mtn*2);
    }
    k_finalize<<<32, 256, 0, stream>>>(part, stats);
    k_norm<<<4608, 256, 0, stream>>>(out, stats, gamma, beta);
}